// Round 12
// baseline (910.160 us; speedup 1.0000x reference)
//
#include <hip/hip_runtime.h>

typedef unsigned short ushort_t;
typedef __bf16 bf16x8 __attribute__((ext_vector_type(8)));
typedef float f32x4 __attribute__((ext_vector_type(4)));
typedef int i32x4_t __attribute__((ext_vector_type(4)));

#define PACK_W_ELEMS (8*9*8*512)           // 294912 bf16 per LSTM: [wave8][kt9][gu8][512]
#define HEAD_ELEMS   (9*512)               // 1 n-tile x 9 k-tiles
#define PACK_TOTAL   (4*PACK_W_ELEMS + 2*HEAD_ELEMS)
#define FLAG_OFS     PACK_TOTAL            // ushort index of int dtype flag

__device__ __forceinline__ float bf2f(ushort_t u){ return __uint_as_float(((unsigned)u)<<16); }
__device__ __forceinline__ ushort_t f2bf(float f){
  __bf16 h = (__bf16)f;                    // HW RTNE convert (values bounded)
  return *(ushort_t*)&h;
}
__device__ __forceinline__ float rcp_(float x){ return __builtin_amdgcn_rcpf(x); }

__device__ __forceinline__ int sniff_f32(const ushort_t* w){
  int f32 = 0;
  #pragma unroll
  for (int i = 0; i < 32; ++i){
    float f = bf2f(w[2*i]);
    if (!(f > -8.f && f < 8.f)) f32 = 1;
  }
  return f32;
}
__device__ __forceinline__ float ldin(const ushort_t* p, int i, int f32){
  return f32 ? ((const float*)p)[i] : bf2f(p[i]);
}
__device__ __forceinline__ ushort_t ldw(const ushort_t* p, int i, int f32){
  return f32 ? f2bf(((const float*)p)[i]) : p[i];
}

// ---------------- pack kernel (identical to r9) ----------------
struct PackArgs {
  const ushort_t* wih[4]; const ushort_t* whh[4];
  const ushort_t* bih[4]; const ushort_t* bhh[4];
  const ushort_t* fcsp_w; const ushort_t* fcsp_b;
  const ushort_t* fccr_w; const ushort_t* fccr_b;
  const ushort_t* emb_w;  const ushort_t* emb_b;
  ushort_t* ws;
};

__global__ void pack_kernel(PackArgs a){
  const int f32 = sniff_f32(a.whh[0]);
  int idx = blockIdx.x*256 + threadIdx.x;
  if (blockIdx.x == 0 && threadIdx.x == 0) *(int*)(a.ws + FLAG_OFS) = f32;
  const int total_w = 4*PACK_W_ELEMS;
  if (idx < total_w){
    int l = idx / PACK_W_ELEMS;
    int r = idx % PACK_W_ELEMS;
    int j = r & 7;
    int lane = (r>>3) & 63;
    int tile = r >> 9;            // (wv*9 + kt)*8 + gu
    int gu = tile & 7;
    int kt = (tile >> 3) % 9;
    int wv = tile / 72;
    int g = gu >> 1, u = gu & 1;
    int n = (g*16 + wv*2 + u)*16 + (lane & 15);
    int k = kt*32 + ((lane>>4)<<3) + j;
    ushort_t v = 0;
    if (k < 256)       v = ldw(a.whh[l], n*256 + k, f32);
    else if (k < 260)  v = ldw(a.wih[l], n*4 + (k-256), f32);
    else if (k == 260) v = f2bf(ldin(a.bih[l], n, f32) + ldin(a.bhh[l], n, f32));
    a.ws[l*PACK_W_ELEMS + r] = v;
    return;
  }
  idx -= total_w;
  if (idx < 2*HEAD_ELEMS){
    int which = idx / HEAD_ELEMS;           // 0 = speed, 1 = cross
    int r = idx % HEAD_ELEMS;
    int j = r & 7; int lane = (r>>3)&63; int kt = r>>9;
    int n = lane & 15; int k = kt*32 + ((lane>>4)<<3) + j;
    ushort_t v = 0;
    if (which == 0){
      if (n < 4){
        if (k < 256)       v = ldw(a.fcsp_w, n*256 + k, f32);
        else if (k == 260) v = f2bf(ldin(a.fcsp_b, n, f32));
      }
    } else {
      if (n < 4){
        if (k < 256)       v = ldw(a.emb_w, n*256 + k, f32);
        else if (k == 260) v = f2bf(ldin(a.emb_b, n, f32));
      } else if (n < 6){
        if (k < 256)       v = ldw(a.fccr_w, (n-4)*256 + k, f32);
        else if (k == 260) v = f2bf(ldin(a.fccr_b, n-4, f32));
      }
    }
    a.ws[total_w + idx] = v;
  }
}

// ---------------- async-B transport helpers ----------------
// Raw barrier: lgkm-drain (LDS producer visibility) + s_barrier, NO vmcnt drain ->
// global_load_lds prefetch stays in flight across region boundaries (T3/T4 pattern).
#define BAR() do { asm volatile("s_waitcnt lgkmcnt(0)" ::: "memory"); \
                   __builtin_amdgcn_s_barrier();                      \
                   asm volatile("" ::: "memory"); } while(0)
#define WAITV4() do { asm volatile("s_waitcnt vmcnt(4)"); __builtin_amdgcn_sched_barrier(0); } while(0)
#define WAITV0() do { asm volatile("s_waitcnt vmcnt(0)"); __builtin_amdgcn_sched_barrier(0); } while(0)
#define WAITL0() do { asm volatile("s_waitcnt lgkmcnt(0)"); __builtin_amdgcn_sched_barrier(0); } while(0)

__device__ __forceinline__ unsigned lds_off(const void* p){
  return (unsigned)(size_t)(const __attribute__((address_space(3))) void*)p;
}
__device__ __forceinline__ bf16x8 dsr16(unsigned off){
  i32x4_t v;
  asm volatile("ds_read_b128 %0, %1" : "=v"(v) : "v"(off));
  return *(bf16x8*)&v;
}
// one half-kt group = 4 KB = 4 x (64 lanes x 16 B); LDS dest wave-uniform, global per-lane
__device__ __forceinline__ void issue4(const ushort_t* gsrc, ushort_t* ldst){
  #pragma unroll
  for (int i = 0; i < 4; ++i)
    __builtin_amdgcn_global_load_lds(
      (const __attribute__((address_space(1))) void*)(gsrc + i*512),
      (__attribute__((address_space(3))) void*)(ldst + i*512), 16, 0, 0);
}

#define MFMA16(H, B0, B1, B2, B3)                                                      \
  acc[0][H+0] = __builtin_amdgcn_mfma_f32_16x16x32_bf16(a0, B0, acc[0][H+0], 0,0,0);   \
  acc[1][H+0] = __builtin_amdgcn_mfma_f32_16x16x32_bf16(a1, B0, acc[1][H+0], 0,0,0);   \
  acc[2][H+0] = __builtin_amdgcn_mfma_f32_16x16x32_bf16(a2, B0, acc[2][H+0], 0,0,0);   \
  acc[3][H+0] = __builtin_amdgcn_mfma_f32_16x16x32_bf16(a3, B0, acc[3][H+0], 0,0,0);   \
  acc[0][H+1] = __builtin_amdgcn_mfma_f32_16x16x32_bf16(a0, B1, acc[0][H+1], 0,0,0);   \
  acc[1][H+1] = __builtin_amdgcn_mfma_f32_16x16x32_bf16(a1, B1, acc[1][H+1], 0,0,0);   \
  acc[2][H+1] = __builtin_amdgcn_mfma_f32_16x16x32_bf16(a2, B1, acc[2][H+1], 0,0,0);   \
  acc[3][H+1] = __builtin_amdgcn_mfma_f32_16x16x32_bf16(a3, B1, acc[3][H+1], 0,0,0);   \
  acc[0][H+2] = __builtin_amdgcn_mfma_f32_16x16x32_bf16(a0, B2, acc[0][H+2], 0,0,0);   \
  acc[1][H+2] = __builtin_amdgcn_mfma_f32_16x16x32_bf16(a1, B2, acc[1][H+2], 0,0,0);   \
  acc[2][H+2] = __builtin_amdgcn_mfma_f32_16x16x32_bf16(a2, B2, acc[2][H+2], 0,0,0);   \
  acc[3][H+2] = __builtin_amdgcn_mfma_f32_16x16x32_bf16(a3, B2, acc[3][H+2], 0,0,0);   \
  acc[0][H+3] = __builtin_amdgcn_mfma_f32_16x16x32_bf16(a0, B3, acc[0][H+3], 0,0,0);   \
  acc[1][H+3] = __builtin_amdgcn_mfma_f32_16x16x32_bf16(a1, B3, acc[1][H+3], 0,0,0);   \
  acc[2][H+3] = __builtin_amdgcn_mfma_f32_16x16x32_bf16(a2, B3, acc[2][H+3], 0,0,0);   \
  acc[3][H+3] = __builtin_amdgcn_mfma_f32_16x16x32_bf16(a3, B3, acc[3][H+3], 0,0,0);

// B values/order identical to r9 (group G = kt*2+half; gu = half*4+j; kt ascending)
// -> bit-identical accumulation. Entry state: groups 0,1 already issued into buf0/buf1.
// Tail issues next region's groups 0,1 -> they deliver during the following wb phase.
__device__ __forceinline__ void gate_gemm(
    unsigned aOff,                      // lds_off(ApX) + lane*16
    unsigned bOff,                      // lds_off(&Bls[0][w][0]) + lane*16
    const ushort_t* __restrict__ bwCur, // global slice + lane*8
    const ushort_t* __restrict__ bwNext,// next region slice + lane*8
    ushort_t* blsW,                     // &Bls[0][w][0] (uniform per wave)
    int hasNext,
    f32x4 (&acc)[4][8])
{
  #pragma unroll
  for (int i = 0; i < 4; ++i)
    #pragma unroll
    for (int j = 0; j < 8; ++j) acc[i][j] = (f32x4){0.f,0.f,0.f,0.f};
  bf16x8 a0, a1, a2, a3;
  const ushort_t* pIss = bwCur + 4096;  // group 2
  #pragma unroll 1
  for (int kt = 0; kt < 8; ++kt){
    // even g=2kt: buf0
    WAITV4();
    bf16x8 b0 = dsr16(bOff + 0);
    bf16x8 b1 = dsr16(bOff + 1024);
    bf16x8 b2 = dsr16(bOff + 2048);
    bf16x8 b3 = dsr16(bOff + 3072);
    {
      const unsigned aK = aOff + (unsigned)kt*1024u;
      a0 = dsr16(aK);
      a1 = dsr16(aK + 9216);
      a2 = dsr16(aK + 18432);
      a3 = dsr16(aK + 27648);
    }
    WAITL0();
    issue4(pIss, blsW);                       // group 2kt+2 -> buf0
    MFMA16(0, b0, b1, b2, b3)
    // odd g=2kt+1: buf1
    WAITV4();
    bf16x8 c0 = dsr16(bOff + 32768);
    bf16x8 c1 = dsr16(bOff + 32768 + 1024);
    bf16x8 c2 = dsr16(bOff + 32768 + 2048);
    bf16x8 c3 = dsr16(bOff + 32768 + 3072);
    WAITL0();
    issue4(pIss + 2048, blsW + 16384);        // group 2kt+3 -> buf1
    MFMA16(4, c0, c1, c2, c3)
    pIss += 4096;
  }
  // kt = 8 (groups 16,17): issue next region's groups 0,1
  {
    WAITV4();
    bf16x8 b0 = dsr16(bOff + 0);
    bf16x8 b1 = dsr16(bOff + 1024);
    bf16x8 b2 = dsr16(bOff + 2048);
    bf16x8 b3 = dsr16(bOff + 3072);
    {
      const unsigned aK = aOff + 8u*1024u;
      a0 = dsr16(aK);
      a1 = dsr16(aK + 9216);
      a2 = dsr16(aK + 18432);
      a3 = dsr16(aK + 27648);
    }
    WAITL0();
    if (hasNext) issue4(bwNext, blsW);        // next g0 -> buf0
    MFMA16(0, b0, b1, b2, b3)
    if (hasNext) { WAITV4(); } else { WAITV0(); }
    bf16x8 c0 = dsr16(bOff + 32768);
    bf16x8 c1 = dsr16(bOff + 32768 + 1024);
    bf16x8 c2 = dsr16(bOff + 32768 + 2048);
    bf16x8 c3 = dsr16(bOff + 32768 + 3072);
    WAITL0();
    if (hasNext) issue4(bwNext + 2048, blsW + 16384);  // next g1 -> buf1
    MFMA16(4, c0, c1, c2, c3)
  }
}

// gate nonlinearity + h writeback (merged-division form, r9) — unchanged math
__device__ __forceinline__ void gates_wb(f32x4 (&acc)[4][8], float (&cw)[4][2][4],
                                         ushort_t* __restrict__ Ap, int wbBase){
  #pragma unroll
  for (int mt = 0; mt < 4; ++mt)
    #pragma unroll
    for (int u = 0; u < 2; ++u)
      #pragma unroll
      for (int r = 0; r < 4; ++r){
        const float i_ = acc[mt][u][r];
        const float f_ = acc[mt][2+u][r];
        const float g_ = acc[mt][4+u][r];
        const float o_ = acc[mt][6+u][r];
        const float ei = __expf(-i_);
        const float ef = __expf(-f_);
        const float eg = __expf(-2.0f*g_);
        const float di = 1.0f + ei, df = 1.0f + ef;
        const float dg = 1.0f + eg, ng = 1.0f - eg;
        const float dig = di*dg;
        const float cn = (cw[mt][u][r]*dig + ng*df) * rcp_(df*dig);
        const float eo = __expf(-o_);
        const float ec = __expf(-2.0f*cn);
        const float hn = (1.0f - ec) * rcp_((1.0f + eo)*(1.0f + ec));
        cw[mt][u][r] = cn;
        Ap[mt*4608 + u*256 + r*8 + wbBase] = f2bf(hn);
      }
}

// ---------------- main kernel: 256 blocks x 64 rows, 512 threads (8 waves) ----------------
// r9 schedule; B transported via per-wave LDS dbuf + global_load_lds with counted vmcnt,
// raw barriers (no vmcnt drain) so next-region prefetch delivers during wb phases.
__global__ __launch_bounds__(512, 2) void pvlstm_main(
    const ushort_t* __restrict__ ws,
    const ushort_t* __restrict__ speed,
    const ushort_t* __restrict__ pos,
    void* __restrict__ outv)
{
  __shared__ ushort_t ApS[4*9*512];    // 36 KB
  __shared__ ushort_t ApP[4*9*512];    // 36 KB
  __shared__ ushort_t xsS[64*64];      // 8 KB
  __shared__ ushort_t xsP[64*64];      // 8 KB
  __shared__ ushort_t Bls[2][8][2048]; // 64 KB  (2 bufs x 8 waves x 4 KB)

  const int f32   = *(const int*)(ws + FLAG_OFS);
  const int tid   = threadIdx.x;
  const int lane  = tid & 63;
  const int w     = tid >> 6;   // 0..7
  const int col16 = lane & 15;
  const int quad  = lane >> 4;
  const int brow0 = blockIdx.x * 64;
  const int wbBase = w*512 + (col16>>3)*128 + quad*32 + (col16&7);

  ushort_t* outu = (ushort_t*)outv;
  float*    outf = (float*)outv;

  const ushort_t* headsp = ws + 4*PACK_W_ELEMS;
  const ushort_t* headcr = headsp + HEAD_ELEMS;
  const ushort_t* aS  = ApS + lane*8;
  const ushort_t* aP  = ApP + lane*8;
  const ushort_t* bwS  = ws + 0*PACK_W_ELEMS + (size_t)w*36864 + (size_t)lane*8;
  const ushort_t* bwP  = ws + 1*PACK_W_ELEMS + (size_t)w*36864 + (size_t)lane*8;
  const ushort_t* bwDS = ws + 2*PACK_W_ELEMS + (size_t)w*36864 + (size_t)lane*8;
  const ushort_t* bwDC = ws + 3*PACK_W_ELEMS + (size_t)w*36864 + (size_t)lane*8;

  ushort_t* blsW = &Bls[0][w][0];
  const unsigned bOff  = lds_off(blsW) + (unsigned)lane*16u;
  const unsigned aOffS = lds_off(ApS) + (unsigned)lane*16u;
  const unsigned aOffP = lds_off(ApP) + (unsigned)lane*16u;

  float cwA[4][2][4], cwB[4][2][4];
  f32x4 acc[4][8];

  // ---- prologue: stage inputs, zero A-packs, bias column, x_sp(0) ----
  for (int i = tid; i < 4096; i += 512){
    int gi = (brow0 + (i>>6))*64 + (i&63);
    xsS[i] = f2bf(ldin(speed, gi, f32));
    xsP[i] = f2bf(ldin(pos,   gi, f32));
  }
  for (int i = tid; i < 4*9*512/2; i += 512){
    ((unsigned*)ApS)[i] = 0u; ((unsigned*)ApP)[i] = 0u;
  }
  #pragma unroll
  for (int mt = 0; mt < 4; ++mt)
    #pragma unroll
    for (int u = 0; u < 2; ++u)
      #pragma unroll
      for (int r = 0; r < 4; ++r){ cwA[mt][u][r] = 0.f; cwB[mt][u][r] = 0.f; }
  BAR();
  if (tid < 64){
    ushort_t* xpS = &ApS[((tid>>4)*9 + 8)*512 + (tid&15)*8];
    ushort_t* xpP = &ApP[((tid>>4)*9 + 8)*512 + (tid&15)*8];
    *(uint2*)xpS = *(const uint2*)&xsS[tid*64];    // x_sp(0)
    xpS[4] = (ushort_t)0x3f80;                     // bias 1.0 column
    xpP[4] = (ushort_t)0x3f80;
  }
  BAR();
  // prime: first gemm's groups 0,1
  issue4(bwS,        blsW);
  issue4(bwS + 2048, blsW + 16384);

  // ================= encoders: sp (A) and po (B), interleaved =================
  for (int t = 0; t < 16; ++t){
    // R1: gates_po(t-1)+wb -> ApP ; x_po(t) -> ApP.kt8 ; GEMM_sp(t)  [next = bwP]
    if (t > 0) gates_wb(acc, cwB, ApP, wbBase);
    if (tid < 64)
      *(uint2*)&ApP[((tid>>4)*9 + 8)*512 + (tid&15)*8] = *(const uint2*)&xsP[tid*64 + t*4];
    gate_gemm(aOffS, bOff, bwS, bwP, blsW, 1, acc);
    BAR();
    // R2: gates_sp(t)+wb -> ApS ; x_sp(t+1) -> ApS.kt8 ; GEMM_po(t)  [next = bwS | bwDS]
    gates_wb(acc, cwA, ApS, wbBase);
    if (t < 15 && tid < 64)
      *(uint2*)&ApS[((tid>>4)*9 + 8)*512 + (tid&15)*8] = *(const uint2*)&xsS[tid*64 + t*4 + 4];
    gate_gemm(aOffP, bOff, bwP, (t < 15) ? bwS : bwDS, blsW, 1, acc);
    BAR();
  }
  // ---- encoder epilogue: gates_po(15) (merged form); h0 = h_sp+h_po; c0 in regs ----
  #pragma unroll
  for (int mt = 0; mt < 4; ++mt)
    #pragma unroll
    for (int u = 0; u < 2; ++u)
      #pragma unroll
      for (int r = 0; r < 4; ++r){
        const float i_ = acc[mt][u][r];
        const float f_ = acc[mt][2+u][r];
        const float g_ = acc[mt][4+u][r];
        const float o_ = acc[mt][6+u][r];
        const float ei = __expf(-i_);
        const float ef = __expf(-f_);
        const float eg = __expf(-2.0f*g_);
        const float di = 1.0f + ei, df = 1.0f + ef;
        const float dg = 1.0f + eg, ng = 1.0f - eg;
        const float dig = di*dg;
        const float cn = (cwB[mt][u][r]*dig + ng*df) * rcp_(df*dig);
        const float eo = __expf(-o_);
        const float ec = __expf(-2.0f*cn);
        const float hn = (1.0f - ec) * rcp_((1.0f + eo)*(1.0f + ec));
        const float c0 = cwA[mt][u][r] + cn;
        cwA[mt][u][r] = c0; cwB[mt][u][r] = c0;
        const int ad = mt*4608 + u*256 + r*8 + wbBase;
        ushort_t h0 = f2bf(bf2f(ApS[ad]) + hn);    // h_sp(15) written in R2(15)
        ApS[ad] = h0; ApP[ad] = h0;
      }
  if (tid < 64){
    *(uint2*)&ApS[((tid>>4)*9 + 8)*512 + (tid&15)*8] = *(const uint2*)&xsS[tid*64 + 60];  // x0 sp
    *(uint2*)&ApP[((tid>>4)*9 + 8)*512 + (tid&15)*8] = *(const uint2*)&xsP[tid*64 + 60];  // x0 po
  }
  BAR();

  // ================= decoders: dsp (A, ApS) and dcr (B, ApP), interleaved =================
  for (int t = 0; t < 16; ++t){
    // R1: head_cr(t-1) [waves 4..7] -> out + x_cr(t) ; GEMM_dsp(t)  [next = bwDC]
    if (t > 0 && w >= 4){
      const int mt = w - 4;
      f32x4 hacc = (f32x4){0.f,0.f,0.f,0.f};
      #pragma unroll
      for (int kt = 0; kt < 9; ++kt){
        bf16x8 a  = *(const bf16x8*)&aP[(mt*9+kt)*512];
        bf16x8 bv = *(const bf16x8*)&headcr[((size_t)kt*64 + lane)*8];
        hacc = __builtin_amdgcn_mfma_f32_16x16x32_bf16(a, bv, hacc, 0, 0, 0);
      }
      const int s = col16;
      #pragma unroll
      for (int r = 0; r < 4; ++r){
        float v = fmaxf(hacc[r], 0.f);             // relu
        const float o = __shfl_xor(v, 1, 64);      // pair logits (lanes 4<->5)
        const int m = mt*16 + quad*4 + r;
        if (s < 4){
          ApP[(mt*9+8)*512 + (m&15)*8 + s] = f2bf(v);          // x_cr(t) feedback
        } else if (s < 6){
          const float mx = fmaxf(v, o);
          const float e0 = __expf(v-mx), e1 = __expf(o-mx);
          const float pv = e0*rcp_(e0+e1);                     // softmax2 at t-1
          const int oi = 1048576 + (brow0 + m)*32 + (t-1)*2 + (s-4);
          if (f32) outf[oi] = pv; else outu[oi] = f2bf(pv);
        }
      }
    }
    gate_gemm(aOffS, bOff, bwDS, bwDC, blsW, 1, acc);
    BAR();
    // R2: gates_dsp(t)+wb -> ApS ; GEMM_dcr(t)  [next = bwDS, none at t=15]
    gates_wb(acc, cwA, ApS, wbBase);
    gate_gemm(aOffP, bOff, bwDC, bwDS, blsW, (t < 15) ? 1 : 0, acc);
    BAR();
    // R3: gates_dcr(t)+wb -> ApP ; head_sp(t) [waves 0..3] -> out + x_sp(t+1)
    gates_wb(acc, cwB, ApP, wbBase);
    if (w < 4){
      const int mt = w;
      f32x4 hacc = (f32x4){0.f,0.f,0.f,0.f};
      #pragma unroll
      for (int kt = 0; kt < 9; ++kt){
        bf16x8 a  = *(const bf16x8*)&aS[(mt*9+kt)*512];
        bf16x8 bv = *(const bf16x8*)&headsp[((size_t)kt*64 + lane)*8];
        hacc = __builtin_amdgcn_mfma_f32_16x16x32_bf16(a, bv, hacc, 0, 0, 0);
      }
      const int s = col16;
      if (s < 4){
        #pragma unroll
        for (int r = 0; r < 4; ++r){
          float v = fminf(fmaxf(hacc[r], -100.f), 100.f);      // hardtanh(+-100)
          const int m = mt*16 + quad*4 + r;
          const int oi = (brow0 + m)*64 + t*4 + s;
          if (f32) outf[oi] = v; else outu[oi] = f2bf(v);
          ApS[(mt*9+8)*512 + (m&15)*8 + s] = f2bf(v);          // x_sp(t+1) feedback
        }
      }
    }
    BAR();
  }
  // ---- decoder epilogue: head_cr(15) ----
  if (w >= 4){
    const int mt = w - 4;
    f32x4 hacc = (f32x4){0.f,0.f,0.f,0.f};
    #pragma unroll
    for (int kt = 0; kt < 9; ++kt){
      bf16x8 a  = *(const bf16x8*)&aP[(mt*9+kt)*512];
      bf16x8 bv = *(const bf16x8*)&headcr[((size_t)kt*64 + lane)*8];
      hacc = __builtin_amdgcn_mfma_f32_16x16x32_bf16(a, bv, hacc, 0, 0, 0);
    }
    const int s = col16;
    if (s >= 4 && s < 6){
      #pragma unroll
      for (int r = 0; r < 4; ++r){
        float v = fmaxf(hacc[r], 0.f);
        const float o = __shfl_xor(v, 1, 64);
        const int m = mt*16 + quad*4 + r;
        const float mx = fmaxf(v, o);
        const float e0 = __expf(v-mx), e1 = __expf(o-mx);
        const float pv = e0*rcp_(e0+e1);
        const int oi = 1048576 + (brow0 + m)*32 + 15*2 + (s-4);
        if (f32) outf[oi] = pv; else outu[oi] = f2bf(pv);
      }
    }
  }
}

extern "C" void kernel_launch(void* const* d_in, const int* in_sizes, int n_in,
                              void* d_out, int out_size, void* d_ws, size_t ws_size,
                              hipStream_t stream) {
  PackArgs pa;
  pa.wih[0]=(const ushort_t*)d_in[2];  pa.whh[0]=(const ushort_t*)d_in[3];
  pa.bih[0]=(const ushort_t*)d_in[4];  pa.bhh[0]=(const ushort_t*)d_in[5];
  pa.wih[1]=(const ushort_t*)d_in[6];  pa.whh[1]=(const ushort_t*)d_in[7];
  pa.bih[1]=(const ushort_t*)d_in[8];  pa.bhh[1]=(const ushort_t*)d_in[9];
  pa.wih[2]=(const ushort_t*)d_in[10]; pa.whh[2]=(const ushort_t*)d_in[11];
  pa.bih[2]=(const ushort_t*)d_in[12]; pa.bhh[2]=(const ushort_t*)d_in[13];
  pa.wih[3]=(const ushort_t*)d_in[14]; pa.whh[3]=(const ushort_t*)d_in[15];
  pa.bih[3]=(const ushort_t*)d_in[16]; pa.bhh[3]=(const ushort_t*)d_in[17];
  pa.fcsp_w=(const ushort_t*)d_in[18]; pa.fcsp_b=(const ushort_t*)d_in[19];
  pa.fccr_w=(const ushort_t*)d_in[20]; pa.fccr_b=(const ushort_t*)d_in[21];
  pa.emb_w =(const ushort_t*)d_in[22]; pa.emb_b =(const ushort_t*)d_in[23];
  pa.ws = (ushort_t*)d_ws;

  hipLaunchKernelGGL(pack_kernel, dim3((PACK_TOTAL + 255)/256), dim3(256), 0, stream, pa);
  hipLaunchKernelGGL(pvlstm_main, dim3(256), dim3(512), 0, stream,
      (const ushort_t*)d_ws,
      (const ushort_t*)d_in[0], (const ushort_t*)d_in[1],
      d_out);
}

// Round 13
// 803.729 us; speedup vs baseline: 1.1324x; 1.1324x over previous
//
#include <hip/hip_runtime.h>

typedef unsigned short ushort_t;
typedef __bf16 bf16x8 __attribute__((ext_vector_type(8)));
typedef float f32x4 __attribute__((ext_vector_type(4)));

#define PACK_W_ELEMS (8*9*8*512)           // 294912 bf16 per LSTM: [wave8][kt9][gu8][512]
#define HEAD_ELEMS   (9*512)               // 1 n-tile x 9 k-tiles
#define PACK_TOTAL   (4*PACK_W_ELEMS + 2*HEAD_ELEMS)
#define FLAG_OFS     PACK_TOTAL            // ushort index of int dtype flag

#define L2E  1.4426950408889634f           // log2(e)
#define L2E2 2.8853900817779268f           // 2*log2(e)

__device__ __forceinline__ float bf2f(ushort_t u){ return __uint_as_float(((unsigned)u)<<16); }
__device__ __forceinline__ ushort_t f2bf(float f){
  __bf16 h = (__bf16)f;                    // HW RTNE convert (values bounded)
  return *(ushort_t*)&h;
}
__device__ __forceinline__ float rcp_(float x){ return __builtin_amdgcn_rcpf(x); }
__device__ __forceinline__ float ex2_(float x){ return __builtin_amdgcn_exp2f(x); }

__device__ __forceinline__ int sniff_f32(const ushort_t* w){
  int f32 = 0;
  #pragma unroll
  for (int i = 0; i < 32; ++i){
    float f = bf2f(w[2*i]);
    if (!(f > -8.f && f < 8.f)) f32 = 1;
  }
  return f32;
}
__device__ __forceinline__ float ldin(const ushort_t* p, int i, int f32){
  return f32 ? ((const float*)p)[i] : bf2f(p[i]);
}
__device__ __forceinline__ ushort_t ldw(const ushort_t* p, int i, int f32){
  return f32 ? f2bf(((const float*)p)[i]) : p[i];
}

// ---------------- pack kernel ----------------
// Per-LSTM pack: [wave8][kt9][gu8][512]; tile (wv,kt,g,u) = B-frag of n-tile
// ntg = g*16 + wv*2 + u.  K map: k<256 Whh, 256..259 Wih, k==260 bias row (bih+bhh), else 0.
// exp2-domain prescale: LSTM rows scaled by log2e (gates i,f,o) / 2*log2e (gate g) so the
// MFMA emits pre-activations ready for v_exp_f32 (2^x) without a conversion multiply.
struct PackArgs {
  const ushort_t* wih[4]; const ushort_t* whh[4];
  const ushort_t* bih[4]; const ushort_t* bhh[4];
  const ushort_t* fcsp_w; const ushort_t* fcsp_b;
  const ushort_t* fccr_w; const ushort_t* fccr_b;
  const ushort_t* emb_w;  const ushort_t* emb_b;
  ushort_t* ws;
};

__global__ void pack_kernel(PackArgs a){
  const int f32 = sniff_f32(a.whh[0]);
  int idx = blockIdx.x*256 + threadIdx.x;
  if (blockIdx.x == 0 && threadIdx.x == 0) *(int*)(a.ws + FLAG_OFS) = f32;
  const int total_w = 4*PACK_W_ELEMS;
  if (idx < total_w){
    int l = idx / PACK_W_ELEMS;
    int r = idx % PACK_W_ELEMS;
    int j = r & 7;
    int lane = (r>>3) & 63;
    int tile = r >> 9;            // (wv*9 + kt)*8 + gu
    int gu = tile & 7;
    int kt = (tile >> 3) % 9;
    int wv = tile / 72;
    int g = gu >> 1, u = gu & 1;
    int n = (g*16 + wv*2 + u)*16 + (lane & 15);
    int k = kt*32 + ((lane>>4)<<3) + j;
    const float sc = (g == 2) ? L2E2 : L2E;   // gate g (tanh) uses e^-2x -> 2*log2e
    ushort_t v = 0;
    if (k < 256)       v = f2bf(ldin(a.whh[l], n*256 + k, f32) * sc);
    else if (k < 260)  v = f2bf(ldin(a.wih[l], n*4 + (k-256), f32) * sc);
    else if (k == 260) v = f2bf((ldin(a.bih[l], n, f32) + ldin(a.bhh[l], n, f32)) * sc);
    a.ws[l*PACK_W_ELEMS + r] = v;
    return;
  }
  idx -= total_w;
  if (idx < 2*HEAD_ELEMS){
    int which = idx / HEAD_ELEMS;           // 0 = speed, 1 = cross (heads NOT prescaled)
    int r = idx % HEAD_ELEMS;
    int j = r & 7; int lane = (r>>3)&63; int kt = r>>9;
    int n = lane & 15; int k = kt*32 + ((lane>>4)<<3) + j;
    ushort_t v = 0;
    if (which == 0){
      if (n < 4){
        if (k < 256)       v = ldw(a.fcsp_w, n*256 + k, f32);
        else if (k == 260) v = f2bf(ldin(a.fcsp_b, n, f32));
      }
    } else {
      if (n < 4){
        if (k < 256)       v = ldw(a.emb_w, n*256 + k, f32);
        else if (k == 260) v = f2bf(ldin(a.emb_b, n, f32));
      } else if (n < 6){
        if (k < 256)       v = ldw(a.fccr_w, (n-4)*256 + k, f32);
        else if (k == 260) v = f2bf(ldin(a.fccr_b, n-4, f32));
      }
    }
    a.ws[total_w + idx] = v;
  }
}

// ---------------- device helpers for the main kernel ----------------
// Round-0 software-pipelined gate GEMM; first half-kt B group preloaded by the caller
// (PRE4) so region-entry load latency hides under the preceding gate-VALU (r7, neutral).
#define PRE4(bw, s0, s1, s2, s3)                \
  bf16x8 s0 = *(const bf16x8*)&(bw)[0*512];     \
  bf16x8 s1 = *(const bf16x8*)&(bw)[1*512];     \
  bf16x8 s2 = *(const bf16x8*)&(bw)[2*512];     \
  bf16x8 s3 = *(const bf16x8*)&(bw)[3*512];

__device__ __forceinline__ void gate_gemm(const ushort_t* __restrict__ Aln,   // ApX + lane*8
                                          const ushort_t* __restrict__ bw,   // wave pack + lane*8
                                          f32x4 (&acc)[4][8], int lane,
                                          bf16x8 p0, bf16x8 p1, bf16x8 p2, bf16x8 p3){
  #pragma unroll
  for (int i = 0; i < 4; ++i)
    #pragma unroll
    for (int j = 0; j < 8; ++j) acc[i][j] = (f32x4){0.f,0.f,0.f,0.f};
  const ushort_t* bp = bw;
  #pragma unroll 1
  for (int kt = 0; kt < 9; ++kt){
    // load half1 of this kt (gu 4..7) — consumed after half0's MFMAs
    bf16x8 q0 = *(const bf16x8*)&bp[4*512];
    bf16x8 q1 = *(const bf16x8*)&bp[5*512];
    bf16x8 q2 = *(const bf16x8*)&bp[6*512];
    bf16x8 q3 = *(const bf16x8*)&bp[7*512];
    bf16x8 a0 = *(const bf16x8*)&Aln[(0*9+kt)*512];
    bf16x8 a1 = *(const bf16x8*)&Aln[(1*9+kt)*512];
    bf16x8 a2 = *(const bf16x8*)&Aln[(2*9+kt)*512];
    bf16x8 a3 = *(const bf16x8*)&Aln[(3*9+kt)*512];
    // MFMA half0 (gu 0..3) on the preloaded group
    acc[0][0] = __builtin_amdgcn_mfma_f32_16x16x32_bf16(a0, p0, acc[0][0], 0, 0, 0);
    acc[1][0] = __builtin_amdgcn_mfma_f32_16x16x32_bf16(a1, p0, acc[1][0], 0, 0, 0);
    acc[2][0] = __builtin_amdgcn_mfma_f32_16x16x32_bf16(a2, p0, acc[2][0], 0, 0, 0);
    acc[3][0] = __builtin_amdgcn_mfma_f32_16x16x32_bf16(a3, p0, acc[3][0], 0, 0, 0);
    acc[0][1] = __builtin_amdgcn_mfma_f32_16x16x32_bf16(a0, p1, acc[0][1], 0, 0, 0);
    acc[1][1] = __builtin_amdgcn_mfma_f32_16x16x32_bf16(a1, p1, acc[1][1], 0, 0, 0);
    acc[2][1] = __builtin_amdgcn_mfma_f32_16x16x32_bf16(a2, p1, acc[2][1], 0, 0, 0);
    acc[3][1] = __builtin_amdgcn_mfma_f32_16x16x32_bf16(a3, p1, acc[3][1], 0, 0, 0);
    acc[0][2] = __builtin_amdgcn_mfma_f32_16x16x32_bf16(a0, p2, acc[0][2], 0, 0, 0);
    acc[1][2] = __builtin_amdgcn_mfma_f32_16x16x32_bf16(a1, p2, acc[1][2], 0, 0, 0);
    acc[2][2] = __builtin_amdgcn_mfma_f32_16x16x32_bf16(a2, p2, acc[2][2], 0, 0, 0);
    acc[3][2] = __builtin_amdgcn_mfma_f32_16x16x32_bf16(a3, p2, acc[3][2], 0, 0, 0);
    acc[0][3] = __builtin_amdgcn_mfma_f32_16x16x32_bf16(a0, p3, acc[0][3], 0, 0, 0);
    acc[1][3] = __builtin_amdgcn_mfma_f32_16x16x32_bf16(a1, p3, acc[1][3], 0, 0, 0);
    acc[2][3] = __builtin_amdgcn_mfma_f32_16x16x32_bf16(a2, p3, acc[2][3], 0, 0, 0);
    acc[3][3] = __builtin_amdgcn_mfma_f32_16x16x32_bf16(a3, p3, acc[3][3], 0, 0, 0);
    // prefetch half0 of next kt (hidden under half1's MFMAs)
    if (kt < 8){
      p0 = *(const bf16x8*)&bp[4096 + 0*512];
      p1 = *(const bf16x8*)&bp[4096 + 1*512];
      p2 = *(const bf16x8*)&bp[4096 + 2*512];
      p3 = *(const bf16x8*)&bp[4096 + 3*512];
    }
    // MFMA half1 (gu 4..7)
    acc[0][4] = __builtin_amdgcn_mfma_f32_16x16x32_bf16(a0, q0, acc[0][4], 0, 0, 0);
    acc[1][4] = __builtin_amdgcn_mfma_f32_16x16x32_bf16(a1, q0, acc[1][4], 0, 0, 0);
    acc[2][4] = __builtin_amdgcn_mfma_f32_16x16x32_bf16(a2, q0, acc[2][4], 0, 0, 0);
    acc[3][4] = __builtin_amdgcn_mfma_f32_16x16x32_bf16(a3, q0, acc[3][4], 0, 0, 0);
    acc[0][5] = __builtin_amdgcn_mfma_f32_16x16x32_bf16(a0, q1, acc[0][5], 0, 0, 0);
    acc[1][5] = __builtin_amdgcn_mfma_f32_16x16x32_bf16(a1, q1, acc[1][5], 0, 0, 0);
    acc[2][5] = __builtin_amdgcn_mfma_f32_16x16x32_bf16(a2, q1, acc[2][5], 0, 0, 0);
    acc[3][5] = __builtin_amdgcn_mfma_f32_16x16x32_bf16(a3, q1, acc[3][5], 0, 0, 0);
    acc[0][6] = __builtin_amdgcn_mfma_f32_16x16x32_bf16(a0, q2, acc[0][6], 0, 0, 0);
    acc[1][6] = __builtin_amdgcn_mfma_f32_16x16x32_bf16(a1, q2, acc[1][6], 0, 0, 0);
    acc[2][6] = __builtin_amdgcn_mfma_f32_16x16x32_bf16(a2, q2, acc[2][6], 0, 0, 0);
    acc[3][6] = __builtin_amdgcn_mfma_f32_16x16x32_bf16(a3, q2, acc[3][6], 0, 0, 0);
    acc[0][7] = __builtin_amdgcn_mfma_f32_16x16x32_bf16(a0, q3, acc[0][7], 0, 0, 0);
    acc[1][7] = __builtin_amdgcn_mfma_f32_16x16x32_bf16(a1, q3, acc[1][7], 0, 0, 0);
    acc[2][7] = __builtin_amdgcn_mfma_f32_16x16x32_bf16(a2, q3, acc[2][7], 0, 0, 0);
    acc[3][7] = __builtin_amdgcn_mfma_f32_16x16x32_bf16(a3, q3, acc[3][7], 0, 0, 0);
    bp += 4096;
  }
}

// gate nonlinearity + h writeback; acc idx: i->u, f->2+u, g->4+u, o->6+u.
// exp2-domain pre-activations (weights prescaled): ei=2^-i', ef=2^-f', eg=2^-g',
// eo=2^-o' are single v_exp each (negate is a free modifier); only ec needs a mul.
//   cn = (c*di*dg + ng*df) / (df*di*dg)        [== sigm(f)*c + sigm(i)*tanh(g)]
//   hn = (1-ec) / ((1+eo)*(1+ec)),  ec = 2^(-2*log2e*cn)
__device__ __forceinline__ void gates_wb(f32x4 (&acc)[4][8], float (&cw)[4][2][4],
                                         ushort_t* __restrict__ Ap, int wbBase){
  #pragma unroll
  for (int mt = 0; mt < 4; ++mt)
    #pragma unroll
    for (int u = 0; u < 2; ++u)
      #pragma unroll
      for (int r = 0; r < 4; ++r){
        const float ei = ex2_(-acc[mt][u][r]);
        const float ef = ex2_(-acc[mt][2+u][r]);
        const float eg = ex2_(-acc[mt][4+u][r]);
        const float di = 1.0f + ei, df = 1.0f + ef;
        const float dg = 1.0f + eg, ng = 1.0f - eg;
        const float dig = di*dg;
        const float cn = (cw[mt][u][r]*dig + ng*df) * rcp_(df*dig);
        const float eo = ex2_(-acc[mt][6+u][r]);
        const float ec = ex2_(-L2E2*cn);
        const float hn = (1.0f - ec) * rcp_((1.0f + eo)*(1.0f + ec));
        cw[mt][u][r] = cn;
        Ap[mt*4608 + u*256 + r*8 + wbBase] = f2bf(hn);
      }
}

// ---------------- main kernel: 256 blocks x 64 rows, 512 threads (8 waves) ----------------
// r9 structure (best measured 819us) + exp2-domain gate math (-4 v_mul/elem).
__global__ __launch_bounds__(512, 2) void pvlstm_main(
    const ushort_t* __restrict__ ws,
    const ushort_t* __restrict__ speed,
    const ushort_t* __restrict__ pos,
    void* __restrict__ outv)
{
  __shared__ ushort_t ApS[4*9*512];   // A-pack speed-enc / speed-dec (36 KB)
  __shared__ ushort_t ApP[4*9*512];   // A-pack pos-enc / cross-dec   (36 KB)
  __shared__ ushort_t xsS[64*64];     // staged speed inputs (8 KB)
  __shared__ ushort_t xsP[64*64];     // staged pos inputs   (8 KB)
  __shared__ float    ostS[64*64];    // speed outputs stage (16 KB)
  __shared__ float    ostC[64*32];    // crossing outputs stage (8 KB)

  const int f32   = *(const int*)(ws + FLAG_OFS);
  const int tid   = threadIdx.x;
  const int lane  = tid & 63;
  const int w     = tid >> 6;   // 0..7
  const int col16 = lane & 15;
  const int quad  = lane >> 4;
  const int brow0 = blockIdx.x * 64;
  const int wbBase = w*512 + (col16>>3)*128 + quad*32 + (col16&7);

  ushort_t* outu = (ushort_t*)outv;
  float*    outf = (float*)outv;

  const ushort_t* headsp = ws + 4*PACK_W_ELEMS;
  const ushort_t* headcr = headsp + HEAD_ELEMS;
  const ushort_t* aS  = ApS + lane*8;
  const ushort_t* aP  = ApP + lane*8;
  const ushort_t* bwS  = ws + 0*PACK_W_ELEMS + (size_t)w*36864 + (size_t)lane*8;
  const ushort_t* bwP  = ws + 1*PACK_W_ELEMS + (size_t)w*36864 + (size_t)lane*8;
  const ushort_t* bwDS = ws + 2*PACK_W_ELEMS + (size_t)w*36864 + (size_t)lane*8;
  const ushort_t* bwDC = ws + 3*PACK_W_ELEMS + (size_t)w*36864 + (size_t)lane*8;

  float cwA[4][2][4], cwB[4][2][4];
  f32x4 acc[4][8];

  // ---- prologue: stage inputs, zero A-packs, bias column, x_sp(0) ----
  for (int i = tid; i < 4096; i += 512){
    int gi = (brow0 + (i>>6))*64 + (i&63);
    xsS[i] = f2bf(ldin(speed, gi, f32));
    xsP[i] = f2bf(ldin(pos,   gi, f32));
  }
  for (int i = tid; i < 4*9*512/2; i += 512){
    ((unsigned*)ApS)[i] = 0u; ((unsigned*)ApP)[i] = 0u;
  }
  #pragma unroll
  for (int mt = 0; mt < 4; ++mt)
    #pragma unroll
    for (int u = 0; u < 2; ++u)
      #pragma unroll
      for (int r = 0; r < 4; ++r){ cwA[mt][u][r] = 0.f; cwB[mt][u][r] = 0.f; }
  __syncthreads();
  if (tid < 64){
    ushort_t* xpS = &ApS[((tid>>4)*9 + 8)*512 + (tid&15)*8];
    ushort_t* xpP = &ApP[((tid>>4)*9 + 8)*512 + (tid&15)*8];
    *(uint2*)xpS = *(const uint2*)&xsS[tid*64];    // x_sp(0)
    xpS[4] = (ushort_t)0x3f80;                     // bias 1.0 column
    xpP[4] = (ushort_t)0x3f80;
  }
  __syncthreads();

  // ================= encoders: sp (A) and po (B), interleaved =================
  for (int t = 0; t < 16; ++t){
    // R1: [preload B_sp] gates_po(t-1)+wb -> ApP ; x_po(t) -> ApP.kt8 ; GEMM_sp(t)
    {
      PRE4(bwS, s0, s1, s2, s3)
      if (t > 0) gates_wb(acc, cwB, ApP, wbBase);
      if (tid < 64)
        *(uint2*)&ApP[((tid>>4)*9 + 8)*512 + (tid&15)*8] = *(const uint2*)&xsP[tid*64 + t*4];
      gate_gemm(aS, bwS, acc, lane, s0, s1, s2, s3);
    }
    __syncthreads();
    // R2: [preload B_po] gates_sp(t)+wb -> ApS ; x_sp(t+1) -> ApS.kt8 ; GEMM_po(t)
    {
      PRE4(bwP, s0, s1, s2, s3)
      gates_wb(acc, cwA, ApS, wbBase);
      if (t < 15 && tid < 64)
        *(uint2*)&ApS[((tid>>4)*9 + 8)*512 + (tid&15)*8] = *(const uint2*)&xsS[tid*64 + t*4 + 4];
      gate_gemm(aP, bwP, acc, lane, s0, s1, s2, s3);
    }
    __syncthreads();
  }
  // ---- encoder epilogue: gates_po(15) (exp2 form); h0 = h_sp+h_po; c0 in regs ----
  #pragma unroll
  for (int mt = 0; mt < 4; ++mt)
    #pragma unroll
    for (int u = 0; u < 2; ++u)
      #pragma unroll
      for (int r = 0; r < 4; ++r){
        const float ei = ex2_(-acc[mt][u][r]);
        const float ef = ex2_(-acc[mt][2+u][r]);
        const float eg = ex2_(-acc[mt][4+u][r]);
        const float di = 1.0f + ei, df = 1.0f + ef;
        const float dg = 1.0f + eg, ng = 1.0f - eg;
        const float dig = di*dg;
        const float cn = (cwB[mt][u][r]*dig + ng*df) * rcp_(df*dig);
        const float eo = ex2_(-acc[mt][6+u][r]);
        const float ec = ex2_(-L2E2*cn);
        const float hn = (1.0f - ec) * rcp_((1.0f + eo)*(1.0f + ec));
        const float c0 = cwA[mt][u][r] + cn;
        cwA[mt][u][r] = c0; cwB[mt][u][r] = c0;
        const int ad = mt*4608 + u*256 + r*8 + wbBase;
        ushort_t h0 = f2bf(bf2f(ApS[ad]) + hn);    // h_sp(15) written in R2(15)
        ApS[ad] = h0; ApP[ad] = h0;
      }
  if (tid < 64){
    *(uint2*)&ApS[((tid>>4)*9 + 8)*512 + (tid&15)*8] = *(const uint2*)&xsS[tid*64 + 60];  // x0 sp
    *(uint2*)&ApP[((tid>>4)*9 + 8)*512 + (tid&15)*8] = *(const uint2*)&xsP[tid*64 + 60];  // x0 po
  }
  __syncthreads();

  // ================= decoders: dsp (A, ApS) and dcr (B, ApP), interleaved =================
  for (int t = 0; t < 16; ++t){
    // R1: [preload B_dsp] head_cr(t-1) [waves 4..7] -> ostC + x_cr(t) ; GEMM_dsp(t)
    {
      PRE4(bwDS, s0, s1, s2, s3)
      if (t > 0 && w >= 4){
        const int mt = w - 4;
        f32x4 hacc = (f32x4){0.f,0.f,0.f,0.f};
        #pragma unroll
        for (int kt = 0; kt < 9; ++kt){
          bf16x8 a  = *(const bf16x8*)&aP[(mt*9+kt)*512];
          bf16x8 bv = *(const bf16x8*)&headcr[((size_t)kt*64 + lane)*8];
          hacc = __builtin_amdgcn_mfma_f32_16x16x32_bf16(a, bv, hacc, 0, 0, 0);
        }
        const int s = col16;
        #pragma unroll
        for (int r = 0; r < 4; ++r){
          float v = fmaxf(hacc[r], 0.f);             // relu
          const float o = __shfl_xor(v, 1, 64);      // pair logits (lanes 4<->5)
          const int m = mt*16 + quad*4 + r;
          if (s < 4){
            ApP[(mt*9+8)*512 + (m&15)*8 + s] = f2bf(v);          // x_cr(t) feedback
          } else if (s < 6){
            const float mx = fmaxf(v, o);
            const float e0 = __expf(v-mx), e1 = __expf(o-mx);
            ostC[m*32 + (t-1)*2 + (s-4)] = e0*rcp_(e0+e1);       // softmax2 at t-1
          }
        }
      }
      gate_gemm(aS, bwDS, acc, lane, s0, s1, s2, s3);
    }
    __syncthreads();
    // R2: [preload B_dcr] gates_dsp(t)+wb -> ApS ; GEMM_dcr(t)
    {
      PRE4(bwDC, s0, s1, s2, s3)
      gates_wb(acc, cwA, ApS, wbBase);
      gate_gemm(aP, bwDC, acc, lane, s0, s1, s2, s3);
    }
    __syncthreads();
    // R3: gates_dcr(t)+wb -> ApP ; head_sp(t) [waves 0..3] -> ostS + x_sp(t+1)
    gates_wb(acc, cwB, ApP, wbBase);
    if (w < 4){
      const int mt = w;
      f32x4 hacc = (f32x4){0.f,0.f,0.f,0.f};
      #pragma unroll
      for (int kt = 0; kt < 9; ++kt){
        bf16x8 a  = *(const bf16x8*)&aS[(mt*9+kt)*512];
        bf16x8 bv = *(const bf16x8*)&headsp[((size_t)kt*64 + lane)*8];
        hacc = __builtin_amdgcn_mfma_f32_16x16x32_bf16(a, bv, hacc, 0, 0, 0);
      }
      const int s = col16;
      if (s < 4){
        #pragma unroll
        for (int r = 0; r < 4; ++r){
          float v = fminf(fmaxf(hacc[r], -100.f), 100.f);      // hardtanh(+-100)
          const int m = mt*16 + quad*4 + r;
          ostS[m*64 + t*4 + s] = v;
          ApS[(mt*9+8)*512 + (m&15)*8 + s] = f2bf(v);          // x_sp(t+1) feedback
        }
      }
    }
    __syncthreads();
  }
  // ---- decoder epilogue: head_cr(15) ----
  if (w >= 4){
    const int mt = w - 4;
    f32x4 hacc = (f32x4){0.f,0.f,0.f,0.f};
    #pragma unroll
    for (int kt = 0; kt < 9; ++kt){
      bf16x8 a  = *(const bf16x8*)&aP[(mt*9+kt)*512];
      bf16x8 bv = *(const bf16x8*)&headcr[((size_t)kt*64 + lane)*8];
      hacc = __builtin_amdgcn_mfma_f32_16x16x32_bf16(a, bv, hacc, 0, 0, 0);
    }
    const int s = col16;
    if (s >= 4 && s < 6){
      #pragma unroll
      for (int r = 0; r < 4; ++r){
        float v = fmaxf(hacc[r], 0.f);
        const float o = __shfl_xor(v, 1, 64);
        const int m = mt*16 + quad*4 + r;
        const float mx = fmaxf(v, o);
        const float e0 = __expf(v-mx), e1 = __expf(o-mx);
        ostC[m*32 + 15*2 + (s-4)] = e0*rcp_(e0+e1);
      }
    }
  }
  __syncthreads();

  // ---- coalesced output flush ----
  for (int i = tid; i < 4096; i += 512){
    const int oi = (brow0 + (i>>6))*64 + (i&63);
    const float v = ostS[i];
    if (f32) outf[oi] = v; else outu[oi] = f2bf(v);
  }
  for (int i = tid; i < 2048; i += 512){
    const int oi = 1048576 + (brow0 + (i>>5))*32 + (i&31);
    const float v = ostC[i];
    if (f32) outf[oi] = v; else outu[oi] = f2bf(v);
  }
}

extern "C" void kernel_launch(void* const* d_in, const int* in_sizes, int n_in,
                              void* d_out, int out_size, void* d_ws, size_t ws_size,
                              hipStream_t stream) {
  PackArgs pa;
  pa.wih[0]=(const ushort_t*)d_in[2];  pa.whh[0]=(const ushort_t*)d_in[3];
  pa.bih[0]=(const ushort_t*)d_in[4];  pa.bhh[0]=(const ushort_t*)d_in[5];
  pa.wih[1]=(const ushort_t*)d_in[6];  pa.whh[1]=(const ushort_t*)d_in[7];
  pa.bih[1]=(const ushort_t*)d_in[8];  pa.bhh[1]=(const ushort_t*)d_in[9];
  pa.wih[2]=(const ushort_t*)d_in[10]; pa.whh[2]=(const ushort_t*)d_in[11];
  pa.bih[2]=(const ushort_t*)d_in[12]; pa.bhh[2]=(const ushort_t*)d_in[13];
  pa.wih[3]=(const ushort_t*)d_in[14]; pa.whh[3]=(const ushort_t*)d_in[15];
  pa.bih[3]=(const ushort_t*)d_in[16]; pa.bhh[3]=(const ushort_t*)d_in[17];
  pa.fcsp_w=(const ushort_t*)d_in[18]; pa.fcsp_b=(const ushort_t*)d_in[19];
  pa.fccr_w=(const ushort_t*)d_in[20]; pa.fccr_b=(const ushort_t*)d_in[21];
  pa.emb_w =(const ushort_t*)d_in[22]; pa.emb_b =(const ushort_t*)d_in[23];
  pa.ws = (ushort_t*)d_ws;

  hipLaunchKernelGGL(pack_kernel, dim3((PACK_TOTAL + 255)/256), dim3(256), 0, stream, pa);
  hipLaunchKernelGGL(pvlstm_main, dim3(256), dim3(512), 0, stream,
      (const ushort_t*)d_ws,
      (const ushort_t*)d_in[0], (const ushort_t*)d_in[1],
      d_out);
}